// Round 8
// baseline (109.471 us; speedup 1.0000x reference)
//
#include <hip/hip_runtime.h>
#include <math.h>

#define EPS 1e-9f

constexpr int Bn = 1024, Dn = 512, Un = 512;
constexpr int BM = 32;      // rows of B per block (2048 blocks = 8/CU)
constexpr int BU = 64;      // cols of U per block
constexpr int DK = 16;      // k-chunk staged in LDS (14KB/block)
constexpr int SPLITD = 8;   // D split across blocks; 16MB ws (proven path)
constexpr int DPB = Dn / SPLITD;    // 64 d per block
constexpr int NCHUNK = DPB / DK;    // 4 chunks

typedef float v4f __attribute__((ext_vector_type(4)));

// XOR swizzle for sL columns: breaks the same-bank pattern of transposed
// staging writes. Bits 3-4 only, preserves float2 alignment of reads.
__device__ __forceinline__ int swz(int d) { return ((d >> 2) & 3) << 3; }

template <bool USE_WS>
__global__ __launch_bounds__(256, 4) void power_layer(
    const float* __restrict__ x, const float* __restrict__ w,
    const float* __restrict__ p, const float* __restrict__ bias,
    float* __restrict__ outp)
{
    __shared__ float sL[DK][BM];   // Lenc = sign(neg)*(log2|x+eps|+64), swizzled cols
    __shared__ float sP[DK][BU];   // p
    __shared__ float sW[DK][BU];   // w
    __shared__ float sWX[DK][BU];  // odd(p) ? -w : w

    const int tid = threadIdx.x;
    const int tx  = tid & 15;
    const int ty  = tid >> 4;
    const int tx4 = tx * 4;
    const int ty2 = ty * 2;
    const int ub = blockIdx.x * BU;
    const int bb = blockIdx.y * BM;
    const int d0 = blockIdx.z * DPB;

    // staging coordinates (chunk-invariant)
    const int xr  = tid >> 2;          // 0..63 (only tid<128 -> 0..31 used)
    const int xdq = (tid & 3) << 2;    // 0,4,8,12
    const int pd  = tid >> 4;          // 0..15
    const int puq = (tid & 15) << 2;   // 0..60

    // ---- prologue: load chunk 0 into registers ----
    float4 xv = {}, pv = {}, wv = {};
    if (tid < 128)
        xv = *reinterpret_cast<const float4*>(&x[(size_t)(bb + xr) * Dn + d0 + xdq]);
    {
        const size_t gi = (size_t)(d0 + pd) * Un + ub + puq;
        pv = *reinterpret_cast<const float4*>(&p[gi]);
        wv = *reinterpret_cast<const float4*>(&w[gi]);
    }

    v4f acc[2] = {};   // 2 rows x 4 cols per thread

    for (int ch = 0; ch < NCHUNK; ++ch) {
        // ---- transform staged regs (vmcnt wait lands here, after prev compute) ----
        float Lenc[4];
        if (tid < 128) {
            const float* xs = reinterpret_cast<const float*>(&xv);
            #pragma unroll
            for (int j = 0; j < 4; ++j) {
                const float xe = xs[j] + EPS;
                const float La = __builtin_amdgcn_logf(fabsf(xe)) + 64.0f;
                Lenc[j] = (xe < 0.0f) ? -La : La;
            }
        }
        float4 wxv;
        {
            const float* ps  = reinterpret_cast<const float*>(&pv);
            const float* wsv = reinterpret_cast<const float*>(&wv);
            float* wxs = reinterpret_cast<float*>(&wxv);
            #pragma unroll
            for (int j = 0; j < 4; ++j) {
                const bool odd = (fmodf(ps[j], 2.0f) != 0.0f);
                wxs[j] = odd ? -wsv[j] : wsv[j];
            }
        }

        __syncthreads();   // previous chunk's LDS readers done
        if (tid < 128) {
            #pragma unroll
            for (int j = 0; j < 4; ++j) {
                const int dd = xdq + j;
                sL[dd][xr ^ swz(dd)] = Lenc[j];
            }
        }
        *reinterpret_cast<float4*>(&sP[pd][puq])  = pv;
        *reinterpret_cast<float4*>(&sW[pd][puq])  = wv;
        *reinterpret_cast<float4*>(&sWX[pd][puq]) = wxv;
        __syncthreads();   // LDS ready (drains only LDS writes)

        // ---- prefetch next chunk's globals; latency hides under compute ----
        if (ch + 1 < NCHUNK) {
            const int db = d0 + (ch + 1) * DK;
            if (tid < 128)
                xv = *reinterpret_cast<const float4*>(&x[(size_t)(bb + xr) * Dn + db + xdq]);
            const size_t gi = (size_t)(db + pd) * Un + ub + puq;
            pv = *reinterpret_cast<const float4*>(&p[gi]);
            wv = *reinterpret_cast<const float4*>(&w[gi]);
        }

        // ---- inner loop: per d, per-row ADDRESS-selected weight fragment ----
        #pragma unroll 4
        for (int d = 0; d < DK; ++d) {
            const float2 Lv = *reinterpret_cast<const float2*>(&sL[d][ty2 ^ swz(d)]);
            const v4f    Pv = *reinterpret_cast<const v4f*>(&sP[d][tx4]);
            const float* Ls = reinterpret_cast<const float*>(&Lv);

            #pragma unroll
            for (int r = 0; r < 2; ++r) {
                const float Ld = fabsf(Ls[r]) - 64.0f;
                const bool  ng = Ls[r] < 0.0f;
                const v4f Wsel = *reinterpret_cast<const v4f*>(
                    ng ? &sWX[d][tx4] : &sW[d][tx4]);

                const v4f t = Pv * Ld;            // v_pk_mul_f32 x2
                v4f e;
                #pragma unroll
                for (int c = 0; c < 4; ++c)
                    e[c] = __builtin_amdgcn_exp2f(t[c]);
                acc[r] = __builtin_elementwise_fma(Wsel, e, acc[r]);  // v_pk_fma_f32 x2
            }
        }
        __syncthreads();   // safe to overwrite LDS next iteration
    }

    if (USE_WS) {
        // plain coalesced partial stores: ws[z][b][u]
        float* dst = outp + ((size_t)blockIdx.z * Bn + bb + ty2) * Un + ub + tx4;
        #pragma unroll
        for (int r = 0; r < 2; ++r)
            *reinterpret_cast<v4f*>(dst + (size_t)r * Un) = acc[r];
    } else {
        if (blockIdx.z == 0) {
            const v4f bv = *reinterpret_cast<const v4f*>(&bias[ub + tx4]);
            #pragma unroll
            for (int r = 0; r < 2; ++r)
                acc[r] += bv;
        }
        #pragma unroll
        for (int r = 0; r < 2; ++r) {
            const int row = bb + ty2 + r;
            #pragma unroll
            for (int c = 0; c < 4; ++c)
                atomicAdd(&outp[(size_t)row * Un + ub + tx4 + c], acc[r][c]);
        }
    }
}

// out[b,u] = sum_z ws[z][b][u] + bias[u]   (float4 per thread)
__global__ __launch_bounds__(256) void reduce_ws(
    const float* __restrict__ ws, const float* __restrict__ bias,
    float* __restrict__ out)
{
    const int nf4 = (Bn * Un) / 4;   // 131072
    const int i = blockIdx.x * 256 + threadIdx.x;
    if (i >= nf4) return;
    const v4f* w4 = reinterpret_cast<const v4f*>(ws);
    v4f a = w4[i];
    #pragma unroll
    for (int z = 1; z < SPLITD; ++z)
        a += w4[(size_t)z * nf4 + i];
    a += reinterpret_cast<const v4f*>(bias)[i & (Un / 4 - 1)];
    reinterpret_cast<v4f*>(out)[i] = a;
}

extern "C" void kernel_launch(void* const* d_in, const int* in_sizes, int n_in,
                              void* d_out, int out_size, void* d_ws, size_t ws_size,
                              hipStream_t stream) {
    const float* x = (const float*)d_in[0];
    const float* w = (const float*)d_in[1];
    const float* p = (const float*)d_in[2];
    const float* b = (const float*)d_in[3];
    float* out = (float*)d_out;

    const dim3 grid(Un / BU, Bn / BM, SPLITD);   // 8 x 32 x 8 = 2048 blocks
    const size_t need = (size_t)SPLITD * Bn * Un * sizeof(float);   // 16 MB

    if (ws_size >= need) {
        float* wsf = (float*)d_ws;
        power_layer<true><<<grid, dim3(256), 0, stream>>>(x, w, p, b, wsf);
        reduce_ws<<<dim3((Bn * Un / 4 + 255) / 256), dim3(256), 0, stream>>>(wsf, b, out);
    } else {
        hipMemsetAsync(out, 0, (size_t)out_size * sizeof(float), stream);
        power_layer<false><<<grid, dim3(256), 0, stream>>>(x, w, p, b, out);
    }
}

// Round 9
// 108.148 us; speedup vs baseline: 1.0122x; 1.0122x over previous
//
#include <hip/hip_runtime.h>
#include <math.h>

#define EPS 1e-9f

constexpr int Bn = 1024, Dn = 512, Un = 512;
constexpr int BM = 32;      // rows of B per block (2048 blocks = 8/CU grid)
constexpr int BU = 64;      // cols of U per block
constexpr int DK = 16;      // p/w chunk staged per buffer
constexpr int SPLITD = 8;   // D split across blocks; 16MB ws (proven path)
constexpr int DPB = Dn / SPLITD;    // 64 d per block
constexpr int NCHUNK = DPB / DK;    // 4 chunks

typedef float v4f __attribute__((ext_vector_type(4)));

// Swizzle for sL columns: staging thread (row=tid>>3, d-base=(tid&7)*8) would
// put 8 lanes of equal row on one bank; xor with (d>>3)<<2 spreads them.
// Multiple of 4 -> float2 read alignment preserved.
__device__ __forceinline__ int swzL(int d) { return ((d >> 3) & 7) << 2; }

template <bool USE_WS>
__global__ __launch_bounds__(256, 4) void power_layer(
    const float* __restrict__ x, const float* __restrict__ w,
    const float* __restrict__ p, const float* __restrict__ bias,
    float* __restrict__ outp)
{
    __shared__ float sL[DPB][BM];      // whole block x-slice, staged ONCE (8KB)
    __shared__ float sP [2][DK][BU];   // p, double-buffered (8KB)
    __shared__ float sW [2][DK][BU];   // w (8KB)
    __shared__ float sWX[2][DK][BU];   // odd(p) ? -w : w (8KB)   -> 32KB total

    const int tid = threadIdx.x;
    const int tx  = tid & 15;
    const int ty  = tid >> 4;
    const int tx4 = tx * 4;
    const int ty2 = ty * 2;
    const int ub = blockIdx.x * BU;
    const int bb = blockIdx.y * BM;
    const int d0 = blockIdx.z * DPB;

    // p/w staging coordinates (chunk-invariant)
    const int pd  = tid >> 4;          // 0..15
    const int puq = (tid & 15) << 2;   // 0..60

    // ---- prologue 1: stage the ENTIRE x-slice (32 rows x 64 d) once ----
    {
        const int xr = tid >> 3;           // 0..31
        const int xd = (tid & 7) << 3;     // 0,8,...,56
        const int sw = (tid & 7) << 2;     // == swzL(xd + j) for j<8
        const float* xrow = &x[(size_t)(bb + xr) * Dn + d0 + xd];
        const float4 xa = *reinterpret_cast<const float4*>(xrow);
        const float4 xb = *reinterpret_cast<const float4*>(xrow + 4);
        const float* s0 = reinterpret_cast<const float*>(&xa);
        const float* s1 = reinterpret_cast<const float*>(&xb);
        #pragma unroll
        for (int j = 0; j < 4; ++j) {
            const float xe = s0[j] + EPS;
            const float La = __builtin_amdgcn_logf(fabsf(xe)) + 64.0f;
            sL[xd + j][xr ^ sw] = (xe < 0.0f) ? -La : La;
        }
        #pragma unroll
        for (int j = 0; j < 4; ++j) {
            const float xe = s1[j] + EPS;
            const float La = __builtin_amdgcn_logf(fabsf(xe)) + 64.0f;
            sL[xd + 4 + j][xr ^ sw] = (xe < 0.0f) ? -La : La;
        }
    }
    // ---- prologue 2: stage p/w chunk 0 into buffer 0 ----
    {
        const size_t gi = (size_t)(d0 + pd) * Un + ub + puq;
        const float4 pv = *reinterpret_cast<const float4*>(&p[gi]);
        const float4 wv = *reinterpret_cast<const float4*>(&w[gi]);
        const float* ps  = reinterpret_cast<const float*>(&pv);
        const float* wsv = reinterpret_cast<const float*>(&wv);
        float4 wxv;
        float* wxs = reinterpret_cast<float*>(&wxv);
        #pragma unroll
        for (int j = 0; j < 4; ++j) {
            const bool odd = (fmodf(ps[j], 2.0f) != 0.0f);
            wxs[j] = odd ? -wsv[j] : wsv[j];
        }
        *reinterpret_cast<float4*>(&sP [0][pd][puq]) = pv;
        *reinterpret_cast<float4*>(&sW [0][pd][puq]) = wv;
        *reinterpret_cast<float4*>(&sWX[0][pd][puq]) = wxv;
    }
    __syncthreads();

    v4f acc[2] = {};   // 2 rows x 4 cols per thread

    for (int ch = 0; ch < NCHUNK; ++ch) {
        const int cur = ch & 1;

        // issue next chunk's global loads BEFORE compute: ~16d of exp work
        // hides the full HBM/L2 latency before the vmcnt wait at transform
        float4 pv, wv;
        if (ch + 1 < NCHUNK) {
            const size_t gi = (size_t)(d0 + (ch + 1) * DK + pd) * Un + ub + puq;
            pv = *reinterpret_cast<const float4*>(&p[gi]);
            wv = *reinterpret_cast<const float4*>(&w[gi]);
        }

        // ---- compute chunk ch from sL + buffer `cur` ----
        #pragma unroll 4
        for (int d = 0; d < DK; ++d) {
            const int dd = ch * DK + d;
            const float2 Lv = *reinterpret_cast<const float2*>(&sL[dd][ty2 ^ swzL(dd)]);
            const v4f    Pv = *reinterpret_cast<const v4f*>(&sP[cur][d][tx4]);
            const float* Ls = reinterpret_cast<const float*>(&Lv);

            #pragma unroll
            for (int r = 0; r < 2; ++r) {
                const float Ld = fabsf(Ls[r]) - 64.0f;
                const bool  ng = Ls[r] < 0.0f;
                const v4f Wsel = *reinterpret_cast<const v4f*>(
                    ng ? &sWX[cur][d][tx4] : &sW[cur][d][tx4]);

                const v4f t = Pv * Ld;            // v_pk_mul_f32 x2
                v4f e;
                #pragma unroll
                for (int c = 0; c < 4; ++c)
                    e[c] = __builtin_amdgcn_exp2f(t[c]);
                acc[r] = __builtin_elementwise_fma(Wsel, e, acc[r]);  // v_pk_fma_f32 x2
            }
        }

        // ---- transform + write NEXT chunk into the other buffer ----
        if (ch + 1 < NCHUNK) {
            const float* ps  = reinterpret_cast<const float*>(&pv);
            const float* wsv = reinterpret_cast<const float*>(&wv);
            float4 wxv;
            float* wxs = reinterpret_cast<float*>(&wxv);
            #pragma unroll
            for (int j = 0; j < 4; ++j) {
                const bool odd = (fmodf(ps[j], 2.0f) != 0.0f);
                wxs[j] = odd ? -wsv[j] : wsv[j];
            }
            *reinterpret_cast<float4*>(&sP [cur ^ 1][pd][puq]) = pv;
            *reinterpret_cast<float4*>(&sW [cur ^ 1][pd][puq]) = wv;
            *reinterpret_cast<float4*>(&sWX[cur ^ 1][pd][puq]) = wxv;
            __syncthreads();   // single rendezvous per chunk
        }
    }

    if (USE_WS) {
        // plain coalesced partial stores: ws[z][b][u]
        float* dst = outp + ((size_t)blockIdx.z * Bn + bb + ty2) * Un + ub + tx4;
        #pragma unroll
        for (int r = 0; r < 2; ++r)
            *reinterpret_cast<v4f*>(dst + (size_t)r * Un) = acc[r];
    } else {
        if (blockIdx.z == 0) {
            const v4f bv = *reinterpret_cast<const v4f*>(&bias[ub + tx4]);
            #pragma unroll
            for (int r = 0; r < 2; ++r)
                acc[r] += bv;
        }
        #pragma unroll
        for (int r = 0; r < 2; ++r) {
            const int row = bb + ty2 + r;
            #pragma unroll
            for (int c = 0; c < 4; ++c)
                atomicAdd(&outp[(size_t)row * Un + ub + tx4 + c], acc[r][c]);
        }
    }
}

// out[b,u] = sum_z ws[z][b][u] + bias[u]   (float4 per thread)
__global__ __launch_bounds__(256) void reduce_ws(
    const float* __restrict__ ws, const float* __restrict__ bias,
    float* __restrict__ out)
{
    const int nf4 = (Bn * Un) / 4;   // 131072
    const int i = blockIdx.x * 256 + threadIdx.x;
    if (i >= nf4) return;
    const v4f* w4 = reinterpret_cast<const v4f*>(ws);
    v4f a = w4[i];
    #pragma unroll
    for (int z = 1; z < SPLITD; ++z)
        a += w4[(size_t)z * nf4 + i];
    a += reinterpret_cast<const v4f*>(bias)[i & (Un / 4 - 1)];
    reinterpret_cast<v4f*>(out)[i] = a;
}

extern "C" void kernel_launch(void* const* d_in, const int* in_sizes, int n_in,
                              void* d_out, int out_size, void* d_ws, size_t ws_size,
                              hipStream_t stream) {
    const float* x = (const float*)d_in[0];
    const float* w = (const float*)d_in[1];
    const float* p = (const float*)d_in[2];
    const float* b = (const float*)d_in[3];
    float* out = (float*)d_out;

    const dim3 grid(Un / BU, Bn / BM, SPLITD);   // 8 x 32 x 8 = 2048 blocks
    const size_t need = (size_t)SPLITD * Bn * Un * sizeof(float);   // 16 MB

    if (ws_size >= need) {
        float* wsf = (float*)d_ws;
        power_layer<true><<<grid, dim3(256), 0, stream>>>(x, w, p, b, wsf);
        reduce_ws<<<dim3((Bn * Un / 4 + 255) / 256), dim3(256), 0, stream>>>(wsf, b, out);
    } else {
        hipMemsetAsync(out, 0, (size_t)out_size * sizeof(float), stream);
        power_layer<false><<<grid, dim3(256), 0, stream>>>(x, w, p, b, out);
    }
}